// Round 8
// baseline (152.100 us; speedup 1.0000x reference)
//
#include <hip/hip_runtime.h>

#define S_LEN 2048
#define HID   768
#define NH    12
#define HD    64
#define BATCH 2
#define GK    768   // GEMM K dim
#define L2E   1.44269504088896340736f
#define QSCL  (0.125f * L2E)

typedef __attribute__((ext_vector_type(8))) short bf16x8;
typedef __attribute__((ext_vector_type(4))) float f32x4;
typedef __attribute__((ext_vector_type(4))) short s16x4;
typedef __attribute__((ext_vector_type(8))) short s16x8;

// fp32 -> bf16 RNE (prep only)
__device__ __forceinline__ unsigned short f2bf(float f) {
    union { float f; unsigned int u; } v; v.f = f;
    unsigned int r = v.u + 0x7fffu + ((v.u >> 16) & 1u);
    return (unsigned short)(r >> 16);
}
// fp32 -> bf16 round-half-up: 1 VALU + hi-half extract (<=1 ulp vs RNE)
__device__ __forceinline__ unsigned short f2bf_hu(float f) {
    union { float f; unsigned int u; } v; v.f = f;
    return (unsigned short)((v.u + 0x8000u) >> 16);
}

// two fp32 -> packed bf16 pair (RNE), 1 VALU (no builtin on gfx950).
__device__ __forceinline__ unsigned int cvtpk(float a, float b) {
    unsigned int r;
    asm("v_cvt_pk_bf16_f32 %0, %1, %2" : "=v"(r) : "v"(a), "v"(b));
    return r;
}

// raw exp2: skip libm guard. Builtin preferred (compiler models TRANS hazard).
#if __has_builtin(__builtin_amdgcn_exp2f)
#define EXP2(x) __builtin_amdgcn_exp2f(x)
#else
__device__ __forceinline__ float EXP2(float x) {
    float r;
    asm volatile("v_exp_f32 %0, %1\n\ts_nop 0" : "=v"(r) : "v"(x));
    return r;
}
#endif

// async global->LDS, 16B per lane, dest = wave-uniform base + lane*16
#define GLL16(gp, lp) __builtin_amdgcn_global_load_lds( \
    (const __attribute__((address_space(1))) unsigned int*)(gp), \
    (__attribute__((address_space(3))) unsigned int*)(lp), 16, 0, 0)

// ---------------------------------------------------------------------------
// Merged prep: blocks [0,3072) convert X fp32->bf16; [3072,4800) transpose+
// convert Wq|Wk|Wv -> Wt; [4800,4804) pre-scale mask by log2(e) into ws.
// Wq rows and later bq are pre-scaled by QSCL.
// ---------------------------------------------------------------------------
__global__ __launch_bounds__(256) void prep_kernel(
    const float* __restrict__ X, const float* __restrict__ Wq,
    const float* __restrict__ Wk, const float* __restrict__ Wv,
    const float* __restrict__ maskg,
    unsigned short* __restrict__ Xb, unsigned short* __restrict__ Wt,
    float* __restrict__ wsm) {
    __shared__ float T[32][33];
    int bid = blockIdx.x;
    if (bid >= 4800) {                   // mask pre-scale: 1024 float4
        int idx = (bid - 4800) * 256 + threadIdx.x;
        float4 v = ((const float4*)maskg)[idx];
        float4 s; s.x = v.x*L2E; s.y = v.y*L2E; s.z = v.z*L2E; s.w = v.w*L2E;
        ((float4*)wsm)[idx] = s;
        return;
    }
    if (bid < 3072) {
        int id = bid * 256 + threadIdx.x;   // one float4 per thread
        float4 v = ((const float4*)X)[id];
        s16x4 o; o[0] = (short)f2bf(v.x); o[1] = (short)f2bf(v.y);
        o[2] = (short)f2bf(v.z); o[3] = (short)f2bf(v.w);
        ((s16x4*)Xb)[id] = o;
        return;
    }
    int t2 = bid - 3072;
    int mat = t2 / 576, t = t2 % 576;
    int tk = t / 24, tn = t % 24;
    const float* W = (mat == 0) ? Wq : (mat == 1) ? Wk : Wv;
    const float scl = (mat == 0) ? QSCL : 1.0f;
    int r  = threadIdx.x >> 3;
    int c4 = (threadIdx.x & 7) * 4;
    float4 v = *(const float4*)&W[(size_t)(tk*32 + r) * GK + tn*32 + c4];
    T[c4+0][r] = v.x; T[c4+1][r] = v.y; T[c4+2][r] = v.z; T[c4+3][r] = v.w;
    __syncthreads();
    s16x4 o;
    o[0] = (short)f2bf(T[r][c4+0] * scl); o[1] = (short)f2bf(T[r][c4+1] * scl);
    o[2] = (short)f2bf(T[r][c4+2] * scl); o[3] = (short)f2bf(T[r][c4+3] * scl);
    *(s16x4*)&Wt[(size_t)(mat*768 + tn*32 + r) * GK + tk*32 + c4] = o;
}

// ---------------------------------------------------------------------------
// Fused QKV GEMM v3: r4's 128(M)x64(N) tile + DOUBLE-BUFFERED LDS 2-phase
// loop (the in-session-proven attn pattern): issue stage(t+1) -> compute(t)
// -> ONE barrier. Halves barrier count (24->12) and overlaps GLL16 flight
// with MFMA. LDS = 2*(16K+8K) = 48 KB -> 3 blocks/CU. 1152 blocks =
// 8 XCDs x 144. Epilogue identical to r4 (known good).
// Q -> TRANSPOSED [B,H,64,S] (pre-scaled), K -> [B,H,S,64], V -> [B,H,64,S].
// ---------------------------------------------------------------------------
__global__ __launch_bounds__(256) void gemm_qkv(
    const unsigned short* __restrict__ Xb, const unsigned short* __restrict__ Wt,
    const float* __restrict__ bq, const float* __restrict__ bk,
    const float* __restrict__ bv,
    unsigned short* __restrict__ qb, unsigned short* __restrict__ kb,
    unsigned short* __restrict__ vb) {
    __shared__ __align__(16) unsigned short As[2][128][64];
    __shared__ __align__(16) unsigned short Bs[2][64][64];

    const int tid = threadIdx.x;
    // bijective XCD swizzle: 1152 = 8 XCDs x 144 (4 M-tiles x 36 N-tiles each)
    const int wgid = blockIdx.y * gridDim.x + blockIdx.x;
    const int virt = (wgid & 7) * 144 + (wgid >> 3);
    const int bm = (virt / 36) * 128;
    const int bn = (virt % 36) * 64;
    const int w = tid >> 6, l = tid & 63, quad = l >> 4, lq = l & 15;
    const int wx = w & 1, wy = w >> 1;

    const int srow = l >> 3, schunk = ((l & 7) ^ (l >> 3)) * 8;
    const unsigned short* aga = Xb + (size_t)(bm + w*32 + srow) * GK + schunk;
    const unsigned short* bga = Wt + (size_t)(bn + w*16 + srow) * GK + schunk;

    const int c0 = ((quad)     ^ (lq & 7)) * 8;
    const int c1 = ((4 + quad) ^ (lq & 7)) * 8;

    f32x4 zero = {0.f, 0.f, 0.f, 0.f};
    f32x4 acc[4][2];
#pragma unroll
    for (int mi = 0; mi < 4; mi++)
#pragma unroll
        for (int ni = 0; ni < 2; ni++) acc[mi][ni] = zero;

    auto stage = [&](int buf, int k0) {
#pragma unroll
        for (int i = 0; i < 4; i++)
            GLL16(aga + k0 + i*8*GK, &As[buf][w*32 + i*8][0]);
#pragma unroll
        for (int i = 0; i < 2; i++)
            GLL16(bga + k0 + i*8*GK, &Bs[buf][w*16 + i*8][0]);
    };

    stage(0, 0);
    __syncthreads();   // drains vmcnt: tile 0 resident

    int buf = 0;
    for (int k0 = 0; k0 < GK; k0 += 64) {
        if (k0 + 64 < GK) stage(buf ^ 1, k0 + 64);
#pragma unroll
        for (int kh = 0; kh < 2; kh++) {
            const int cc = kh ? c1 : c0;
            bf16x8 a[4], b[2];
#pragma unroll
            for (int mi = 0; mi < 4; mi++)
                a[mi] = *(const bf16x8*)&As[buf][wy*64 + mi*16 + lq][cc];
#pragma unroll
            for (int ni = 0; ni < 2; ni++)
                b[ni] = *(const bf16x8*)&Bs[buf][wx*32 + ni*16 + lq][cc];
#pragma unroll
            for (int mi = 0; mi < 4; mi++)
#pragma unroll
                for (int ni = 0; ni < 2; ni++)
                    acc[mi][ni] = __builtin_amdgcn_mfma_f32_16x16x32_bf16(
                        a[mi], b[ni], acc[mi][ni], 0, 0, 0);
        }
        __syncthreads();   // one barrier/step: WAR for next stage + vmcnt drain
        buf ^= 1;
    }

    const int mat = bn / 768;   // block never straddles matrices
    const float* bias = (mat == 0) ? bq : (mat == 1) ? bk : bv;
    const float bscl = (mat == 0) ? QSCL : 1.0f;
    const int nbase = bn % 768;
#pragma unroll
    for (int ni = 0; ni < 2; ni++) {
        int hn = nbase + wx*32 + ni*16 + lq;
        float bval = bias[hn] * bscl;
        int h = hn >> 6, d = hn & 63;
#pragma unroll
        for (int mi = 0; mi < 4; mi++) {
            int m0 = bm + wy*64 + mi*16 + quad*4;
            int b_ = m0 >> 11, s0 = m0 & 2047;
            if (mat != 1) {
                // transposed [B,H,d,S]: 4 consecutive s -> one 8B store
                unsigned short* outp = (mat == 0) ? qb : vb;
                s16x4 pk;
#pragma unroll
                for (int r = 0; r < 4; r++) pk[r] = (short)f2bf_hu(acc[mi][ni][r] + bval);
                *(s16x4*)&outp[((size_t)((b_*NH + h) * HD + d)) * S_LEN + s0] = pk;
            } else {
                size_t base = ((size_t)((b_*NH + h) * S_LEN + s0)) * HD + d;
#pragma unroll
                for (int r = 0; r < 4; r++)
                    kb[base + (size_t)r * HD] = f2bf_hu(acc[mi][ni][r] + bval);
            }
        }
    }
}

// ---------------------------------------------------------------------------
// MFMA flash attention v9 (byte-exact r4 version — known good; v10's
// setprio/V-hoist PARKED: broke numerics r5+r6, mechanism unidentified).
// Block = (b*h, 64 q-rows), 4 waves x 16 q-rows.
// Permuted-K swapped QK^T: K fragment loaded with rows rho(m) so QK^T
// output rows land at the PV A-fragment's lane layout. P built in-register
// (16 exp2 + 8 cvtpk), no LDS round-trip, no cross-lane ops.
// K swizzle fK(row)=(row&3)|((row>>3&1)<<2); V swizzle chunk^(row&7).
// Mask pre-scaled by log2e, per-tile f32x4 loads, folded as MFMA C-init.
// LDS = 16K Ks + 16K Vt = 32 KB.
// ---------------------------------------------------------------------------
__global__ __launch_bounds__(256, 4) void attn_kernel(
    const unsigned short* __restrict__ Qtg, const unsigned short* __restrict__ Kg,
    const unsigned short* __restrict__ Vtg, const float* __restrict__ wsm,
    float* __restrict__ out) {
    __shared__ __align__(16) unsigned short Ks[2][64][64];
    __shared__ __align__(16) unsigned short Vt[2][64][64];

    const int tid = threadIdx.x;
    const int w = tid >> 6, l = tid & 63, quad = l >> 4, lq = l & 15;

    // bijective XCD swizzle (768 = 8 x 96): each XCD owns 3 heads' q-blocks
    const int wgid = blockIdx.y * gridDim.x + blockIdx.x;
    const int virt = (wgid & 7) * 96 + (wgid >> 3);
    const int bh = virt >> 5;
    const int q0 = (virt & 31) * 64;
    const int bi = bh / NH, hi = bh % NH;
    const unsigned short* Kh = Kg + (size_t)bh * S_LEN * HD;
    const unsigned short* Vh = Vtg + (size_t)bh * HD * S_LEN;
    const float* wsmb = wsm + (size_t)bi * S_LEN;

    // Q fragments from Q^T [B,H,d,S] (once per block; pre-scaled by QSCL).
    bf16x8 a0, a1;
    {
        const unsigned short* Qt = Qtg + (size_t)bh * HD * S_LEN + (q0 + w*16 + lq);
#pragma unroll
        for (int j = 0; j < 8; j++) {
            a0[j] = (short)Qt[(size_t)(quad*8 + j) * S_LEN];
            a1[j] = (short)Qt[(size_t)(quad*8 + j + 32) * S_LEN];
        }
    }

    bf16x8 ones;
#pragma unroll
    for (int i = 0; i < 8; i++) ones[i] = (short)0x3F80;   // bf16 1.0

    const int srow = l >> 3;
    // V staging (old swizzle: chunk ^ (row&7))
    const int svchunk = ((l & 7) ^ (l >> 3)) * 8;
    const unsigned short* vga = Vh + (size_t)(w*16 + srow) * S_LEN + svchunk;
    // K staging (swizzle fK(row) = (row&3) | ((row>>3 & 1)<<2));
    // dest rows w*16+i*8+srow: fK = (srow&3) | (i<<2)
    const int ckK = ((l & 7) ^ ((l >> 3) & 3)) * 8;
    const unsigned short* kga0 = Kh + (size_t)(w*16 + srow) * HD + ckK;
    const unsigned short* kga1 = Kh + (size_t)(w*16 + 8 + srow) * HD + (ckK ^ 32);

    // Vt read slots (old pattern)
    const int c0 = ((quad)     ^ (lq & 7)) * 8;
    const int c1 = ((4 + quad) ^ (lq & 7)) * 8;
    // K fragment read: permuted rows rho = krA + {0,4,32,36}; slots via fK
    const int fk  = (lq & 3) | (((lq >> 2) & 1) << 2);
    const int kc0 = (quad ^ fk) * 8;
    const int kc1 = kc0 ^ 32;
    const int krA = (lq >> 2) * 8 + (lq & 3);

    f32x4 zero = {0.f, 0.f, 0.f, 0.f};
    f32x4 o[4], lsum = zero;
#pragma unroll
    for (int ng = 0; ng < 4; ng++) o[ng] = zero;

    auto stage = [&](int buf, int kt) {
        GLL16(kga0 + (size_t)kt*64*HD, &Ks[buf][w*16][0]);
        GLL16(kga1 + (size_t)kt*64*HD, &Ks[buf][w*16 + 8][0]);
        GLL16(vga + kt*64,                   &Vt[buf][w*16][0]);
        GLL16(vga + kt*64 + (size_t)8*S_LEN, &Vt[buf][w*16 + 8][0]);
    };

    // per-lane mask (QK^T C-init): k = quad*8 + {0..3, 4..7, 32..35, 36..39}
    auto ldm = [&](f32x4* dst, int kt) {
        const float* mb = wsmb + kt*64 + quad*8;
        dst[0] = *(const f32x4*)(mb);
        dst[1] = *(const f32x4*)(mb + 4);
        dst[2] = *(const f32x4*)(mb + 32);
        dst[3] = *(const f32x4*)(mb + 36);
    };

    auto compute = [&](int buf, const f32x4* mk) {
        // ---- swapped QK^T with permuted K rows; mask as C-init ----
        // call c: rows rho = krA + roff[c]; st[c][r] = S^T[k=quad*8+off][q=lq]
        f32x4 st[4];
#pragma unroll
        for (int c = 0; c < 4; c++) {
            const int roff = (c & 1) * 4 + (c >> 1) * 32;
            bf16x8 b0 = *(const bf16x8*)&Ks[buf][krA + roff][kc0];
            bf16x8 b1 = *(const bf16x8*)&Ks[buf][krA + roff][kc1];
            f32x4 z = __builtin_amdgcn_mfma_f32_16x16x32_bf16(b0, a0, mk[c], 0, 0, 0);
            st[c]   = __builtin_amdgcn_mfma_f32_16x16x32_bf16(b1, a1, z,     0, 0, 0);
        }

        // ---- softmax numerator fully in-register: exp2 + cvt_pk ----
        union PU { unsigned int d[4]; bf16x8 v; } p0u, p1u;
#pragma unroll
        for (int c = 0; c < 2; c++) {
            float e0 = EXP2(st[c][0]), e1 = EXP2(st[c][1]);
            float e2 = EXP2(st[c][2]), e3 = EXP2(st[c][3]);
            p0u.d[c*2]   = cvtpk(e0, e1);
            p0u.d[c*2+1] = cvtpk(e2, e3);
        }
#pragma unroll
        for (int c = 0; c < 2; c++) {
            float e0 = EXP2(st[2+c][0]), e1 = EXP2(st[2+c][1]);
            float e2 = EXP2(st[2+c][2]), e3 = EXP2(st[2+c][3]);
            p1u.d[c*2]   = cvtpk(e0, e1);
            p1u.d[c*2+1] = cvtpk(e2, e3);
        }
        bf16x8 pa0 = p0u.v, pa1 = p1u.v;

        lsum = __builtin_amdgcn_mfma_f32_16x16x32_bf16(pa0, ones, lsum, 0, 0, 0);
        lsum = __builtin_amdgcn_mfma_f32_16x16x32_bf16(pa1, ones, lsum, 0, 0, 0);

        // ---- PV ----
#pragma unroll
        for (int ng = 0; ng < 4; ng++) {
            bf16x8 v0 = *(const bf16x8*)&Vt[buf][ng*16 + lq][c0];
            bf16x8 v1 = *(const bf16x8*)&Vt[buf][ng*16 + lq][c1];
            f32x4 t = __builtin_amdgcn_mfma_f32_16x16x32_bf16(pa0, v0, o[ng], 0, 0, 0);
            o[ng]   = __builtin_amdgcn_mfma_f32_16x16x32_bf16(pa1, v1, t,     0, 0, 0);
        }
    };

    f32x4 mkA[4], mkB[4];
    ldm(mkA, 0);
    stage(0, 0);
    __syncthreads();   // drains vmcnt (tile 0)

    for (int kt = 0; kt < S_LEN / 64; kt += 2) {
        stage(1, kt + 1); ldm(mkB, kt + 1);
        compute(0, mkA);
        __syncthreads();
        if (kt + 2 < S_LEN / 64) { stage(0, kt + 2); ldm(mkA, kt + 2); }
        compute(1, mkB);
        __syncthreads();
    }

    // epilogue: out[bi, q, hi*64 + d] fp32
#pragma unroll
    for (int r = 0; r < 4; r++) {
        const float inv = 1.0f / lsum[r];
        const int row = q0 + w*16 + quad*4 + r;
#pragma unroll
        for (int ng = 0; ng < 4; ng++)
            out[((size_t)(bi * S_LEN + row)) * HID + hi*HD + ng*16 + lq] = o[ng][r] * inv;
    }
}

extern "C" void kernel_launch(void* const* d_in, const int* in_sizes, int n_in,
                              void* d_out, int out_size, void* d_ws, size_t ws_size,
                              hipStream_t stream) {
    const float* X    = (const float*)d_in[0];
    const float* mask = (const float*)d_in[1];
    const float* Wq   = (const float*)d_in[2];
    const float* bq   = (const float*)d_in[3];
    const float* Wk   = (const float*)d_in[4];
    const float* bk   = (const float*)d_in[5];
    const float* Wv   = (const float*)d_in[6];
    const float* bv   = (const float*)d_in[7];
    float* out = (float*)d_out;

    const size_t per = (size_t)BATCH * NH * S_LEN * HD;  // 3,145,728
    unsigned short* qb = (unsigned short*)d_ws;           // Q^T [B,H,64,S]
    unsigned short* kb = qb + per;                        // K   [B,H,S,64]
    unsigned short* vb = kb + per;                        // V^T [B,H,64,S]
    unsigned short* xb = vb + per;                        // 4096*768
    unsigned short* wt = xb + (size_t)4096 * GK;          // 2304*768
    float* wsm = (float*)(wt + (size_t)2304 * GK);        // 2*2048 f32 (mask*log2e)

    prep_kernel<<<4804, 256, 0, stream>>>(X, Wq, Wk, Wv, mask, xb, wt, wsm);

    dim3 ggrid(36, 32);                   // 1152 blocks, 128x64 tiles
    gemm_qkv<<<ggrid, 256, 0, stream>>>(xb, wt, bq, bk, bv, qb, kb, vb);

    dim3 agrid(S_LEN / 64, BATCH * NH);   // (32, 24) = 768 blocks = 3/CU
    attn_kernel<<<agrid, 256, 0, stream>>>(qb, kb, vb, wsm, out);
}

// Round 10
// 146.985 us; speedup vs baseline: 1.0348x; 1.0348x over previous
//
#include <hip/hip_runtime.h>

#define S_LEN 2048
#define HID   768
#define NH    12
#define HD    64
#define BATCH 2
#define GK    768   // GEMM K dim
#define L2E   1.44269504088896340736f
#define QSCL  (0.125f * L2E)

typedef __attribute__((ext_vector_type(8))) short bf16x8;
typedef __attribute__((ext_vector_type(4))) float f32x4;
typedef __attribute__((ext_vector_type(4))) short s16x4;
typedef __attribute__((ext_vector_type(8))) short s16x8;

// fp32 -> bf16 RNE (prep only)
__device__ __forceinline__ unsigned short f2bf(float f) {
    union { float f; unsigned int u; } v; v.f = f;
    unsigned int r = v.u + 0x7fffu + ((v.u >> 16) & 1u);
    return (unsigned short)(r >> 16);
}
// fp32 -> bf16 round-half-up: 1 VALU + hi-half extract (<=1 ulp vs RNE)
__device__ __forceinline__ unsigned short f2bf_hu(float f) {
    union { float f; unsigned int u; } v; v.f = f;
    return (unsigned short)((v.u + 0x8000u) >> 16);
}

// two fp32 -> packed bf16 pair (RNE), 1 VALU (no builtin on gfx950).
__device__ __forceinline__ unsigned int cvtpk(float a, float b) {
    unsigned int r;
    asm("v_cvt_pk_bf16_f32 %0, %1, %2" : "=v"(r) : "v"(a), "v"(b));
    return r;
}

// raw exp2: skip libm guard. Builtin preferred (compiler models TRANS hazard).
#if __has_builtin(__builtin_amdgcn_exp2f)
#define EXP2(x) __builtin_amdgcn_exp2f(x)
#else
__device__ __forceinline__ float EXP2(float x) {
    float r;
    asm volatile("v_exp_f32 %0, %1\n\ts_nop 0" : "=v"(r) : "v"(x));
    return r;
}
#endif

// async global->LDS, 16B per lane, dest = wave-uniform base + lane*16
#define GLL16(gp, lp) __builtin_amdgcn_global_load_lds( \
    (const __attribute__((address_space(1))) unsigned int*)(gp), \
    (__attribute__((address_space(3))) unsigned int*)(lp), 16, 0, 0)

// ---------------------------------------------------------------------------
// Merged prep: blocks [0,3072) convert X fp32->bf16; [3072,4800) transpose+
// convert Wq|Wk|Wv -> Wt; [4800,4804) pre-scale mask by log2(e) into ws.
// Wq rows and later bq are pre-scaled by QSCL.
// ---------------------------------------------------------------------------
__global__ __launch_bounds__(256) void prep_kernel(
    const float* __restrict__ X, const float* __restrict__ Wq,
    const float* __restrict__ Wk, const float* __restrict__ Wv,
    const float* __restrict__ maskg,
    unsigned short* __restrict__ Xb, unsigned short* __restrict__ Wt,
    float* __restrict__ wsm) {
    __shared__ float T[32][33];
    int bid = blockIdx.x;
    if (bid >= 4800) {                   // mask pre-scale: 1024 float4
        int idx = (bid - 4800) * 256 + threadIdx.x;
        float4 v = ((const float4*)maskg)[idx];
        float4 s; s.x = v.x*L2E; s.y = v.y*L2E; s.z = v.z*L2E; s.w = v.w*L2E;
        ((float4*)wsm)[idx] = s;
        return;
    }
    if (bid < 3072) {
        int id = bid * 256 + threadIdx.x;   // one float4 per thread
        float4 v = ((const float4*)X)[id];
        s16x4 o; o[0] = (short)f2bf(v.x); o[1] = (short)f2bf(v.y);
        o[2] = (short)f2bf(v.z); o[3] = (short)f2bf(v.w);
        ((s16x4*)Xb)[id] = o;
        return;
    }
    int t2 = bid - 3072;
    int mat = t2 / 576, t = t2 % 576;
    int tk = t / 24, tn = t % 24;
    const float* W = (mat == 0) ? Wq : (mat == 1) ? Wk : Wv;
    const float scl = (mat == 0) ? QSCL : 1.0f;
    int r  = threadIdx.x >> 3;
    int c4 = (threadIdx.x & 7) * 4;
    float4 v = *(const float4*)&W[(size_t)(tk*32 + r) * GK + tn*32 + c4];
    T[c4+0][r] = v.x; T[c4+1][r] = v.y; T[c4+2][r] = v.z; T[c4+3][r] = v.w;
    __syncthreads();
    s16x4 o;
    o[0] = (short)f2bf(T[r][c4+0] * scl); o[1] = (short)f2bf(T[r][c4+1] * scl);
    o[2] = (short)f2bf(T[r][c4+2] * scl); o[3] = (short)f2bf(T[r][c4+3] * scl);
    *(s16x4*)&Wt[(size_t)(mat*768 + tn*32 + r) * GK + tk*32 + c4] = o;
}

// ---------------------------------------------------------------------------
// Fused QKV GEMM (r4 version — best measured of 3 verified variants:
// this 128x64 = 147.7 total, 96-tile = 149.8, dbuf = 152.1). bf16 MFMA
// 16x16x32, 128(M)x64(N) tile, BK=64, 1152 blocks = 8 XCDs x 144.
// global_load_lds width=16 staging, XOR-swizzled LDS.
// Q -> TRANSPOSED [B,H,64,S] (pre-scaled), K -> [B,H,S,64], V -> [B,H,64,S].
// ---------------------------------------------------------------------------
__global__ __launch_bounds__(256) void gemm_qkv(
    const unsigned short* __restrict__ Xb, const unsigned short* __restrict__ Wt,
    const float* __restrict__ bq, const float* __restrict__ bk,
    const float* __restrict__ bv,
    unsigned short* __restrict__ qb, unsigned short* __restrict__ kb,
    unsigned short* __restrict__ vb) {
    __shared__ __align__(16) unsigned short As[128][64];
    __shared__ __align__(16) unsigned short Bs[64][64];

    const int tid = threadIdx.x;
    // bijective XCD swizzle: 1152 = 8 XCDs x 144 (4 M-tiles x 36 N-tiles each)
    const int wgid = blockIdx.y * gridDim.x + blockIdx.x;
    const int virt = (wgid & 7) * 144 + (wgid >> 3);
    const int bm = (virt / 36) * 128;
    const int bn = (virt % 36) * 64;
    const int w = tid >> 6, l = tid & 63, quad = l >> 4, lq = l & 15;
    const int wx = w & 1, wy = w >> 1;

    const int srow = l >> 3, schunk = ((l & 7) ^ (l >> 3)) * 8;
    const unsigned short* aga = Xb + (size_t)(bm + w*32 + srow) * GK + schunk;
    const unsigned short* bga = Wt + (size_t)(bn + w*16 + srow) * GK + schunk;

    const int c0 = ((quad)     ^ (lq & 7)) * 8;
    const int c1 = ((4 + quad) ^ (lq & 7)) * 8;

    f32x4 zero = {0.f, 0.f, 0.f, 0.f};
    f32x4 acc[4][2];
#pragma unroll
    for (int mi = 0; mi < 4; mi++)
#pragma unroll
        for (int ni = 0; ni < 2; ni++) acc[mi][ni] = zero;

    for (int k0 = 0; k0 < GK; k0 += 64) {
        __syncthreads();
#pragma unroll
        for (int i = 0; i < 4; i++)
            GLL16(aga + k0 + i*8*GK, &As[w*32 + i*8][0]);
#pragma unroll
        for (int i = 0; i < 2; i++)
            GLL16(bga + k0 + i*8*GK, &Bs[w*16 + i*8][0]);
        __syncthreads();
#pragma unroll
        for (int kh = 0; kh < 2; kh++) {
            const int cc = kh ? c1 : c0;
            bf16x8 a[4], b[2];
#pragma unroll
            for (int mi = 0; mi < 4; mi++)
                a[mi] = *(const bf16x8*)&As[wy*64 + mi*16 + lq][cc];
#pragma unroll
            for (int ni = 0; ni < 2; ni++)
                b[ni] = *(const bf16x8*)&Bs[wx*32 + ni*16 + lq][cc];
#pragma unroll
            for (int mi = 0; mi < 4; mi++)
#pragma unroll
                for (int ni = 0; ni < 2; ni++)
                    acc[mi][ni] = __builtin_amdgcn_mfma_f32_16x16x32_bf16(
                        a[mi], b[ni], acc[mi][ni], 0, 0, 0);
        }
    }

    const int mat = bn / 768;   // block never straddles matrices
    const float* bias = (mat == 0) ? bq : (mat == 1) ? bk : bv;
    const float bscl = (mat == 0) ? QSCL : 1.0f;
    const int nbase = bn % 768;
#pragma unroll
    for (int ni = 0; ni < 2; ni++) {
        int hn = nbase + wx*32 + ni*16 + lq;
        float bval = bias[hn] * bscl;
        int h = hn >> 6, d = hn & 63;
#pragma unroll
        for (int mi = 0; mi < 4; mi++) {
            int m0 = bm + wy*64 + mi*16 + quad*4;
            int b_ = m0 >> 11, s0 = m0 & 2047;
            if (mat != 1) {
                // transposed [B,H,d,S]: 4 consecutive s -> one 8B store
                unsigned short* outp = (mat == 0) ? qb : vb;
                s16x4 pk;
#pragma unroll
                for (int r = 0; r < 4; r++) pk[r] = (short)f2bf_hu(acc[mi][ni][r] + bval);
                *(s16x4*)&outp[((size_t)((b_*NH + h) * HD + d)) * S_LEN + s0] = pk;
            } else {
                size_t base = ((size_t)((b_*NH + h) * S_LEN + s0)) * HD + d;
#pragma unroll
                for (int r = 0; r < 4; r++)
                    kb[base + (size_t)r * HD] = f2bf_hu(acc[mi][ni][r] + bval);
            }
        }
    }
}

// ---------------------------------------------------------------------------
// MFMA flash attention v9 (byte-exact r4 version — the session's verified
// best, passed r4/r7/r8. v10 setprio/V-hoist and v11 2-wave/32q both
// PARKED: each failed at ~1e-2 absmax with no identifiable source defect;
// v9's exact schedule is the known-safe configuration).
// Block = (b*h, 64 q-rows), 4 waves x 16 q-rows.
// Permuted-K swapped QK^T: K fragment loaded with rows rho(m) so QK^T
// output rows land at the PV A-fragment's lane layout. P built in-register
// (16 exp2 + 8 cvtpk), no LDS round-trip, no cross-lane ops.
// K swizzle fK(row)=(row&3)|((row>>3&1)<<2); V swizzle chunk^(row&7).
// Mask pre-scaled by log2e, per-tile f32x4 loads, folded as MFMA C-init.
// LDS = 16K Ks + 16K Vt = 32 KB. Bank conflicts: 0 (measured).
// ---------------------------------------------------------------------------
__global__ __launch_bounds__(256, 4) void attn_kernel(
    const unsigned short* __restrict__ Qtg, const unsigned short* __restrict__ Kg,
    const unsigned short* __restrict__ Vtg, const float* __restrict__ wsm,
    float* __restrict__ out) {
    __shared__ __align__(16) unsigned short Ks[2][64][64];
    __shared__ __align__(16) unsigned short Vt[2][64][64];

    const int tid = threadIdx.x;
    const int w = tid >> 6, l = tid & 63, quad = l >> 4, lq = l & 15;

    // bijective XCD swizzle (768 = 8 x 96): each XCD owns 3 heads' q-blocks
    const int wgid = blockIdx.y * gridDim.x + blockIdx.x;
    const int virt = (wgid & 7) * 96 + (wgid >> 3);
    const int bh = virt >> 5;
    const int q0 = (virt & 31) * 64;
    const int bi = bh / NH, hi = bh % NH;
    const unsigned short* Kh = Kg + (size_t)bh * S_LEN * HD;
    const unsigned short* Vh = Vtg + (size_t)bh * HD * S_LEN;
    const float* wsmb = wsm + (size_t)bi * S_LEN;

    // Q fragments from Q^T [B,H,d,S] (once per block; pre-scaled by QSCL).
    bf16x8 a0, a1;
    {
        const unsigned short* Qt = Qtg + (size_t)bh * HD * S_LEN + (q0 + w*16 + lq);
#pragma unroll
        for (int j = 0; j < 8; j++) {
            a0[j] = (short)Qt[(size_t)(quad*8 + j) * S_LEN];
            a1[j] = (short)Qt[(size_t)(quad*8 + j + 32) * S_LEN];
        }
    }

    bf16x8 ones;
#pragma unroll
    for (int i = 0; i < 8; i++) ones[i] = (short)0x3F80;   // bf16 1.0

    const int srow = l >> 3;
    // V staging (old swizzle: chunk ^ (row&7))
    const int svchunk = ((l & 7) ^ (l >> 3)) * 8;
    const unsigned short* vga = Vh + (size_t)(w*16 + srow) * S_LEN + svchunk;
    // K staging (swizzle fK(row) = (row&3) | ((row>>3 & 1)<<2));
    // dest rows w*16+i*8+srow: fK = (srow&3) | (i<<2)
    const int ckK = ((l & 7) ^ ((l >> 3) & 3)) * 8;
    const unsigned short* kga0 = Kh + (size_t)(w*16 + srow) * HD + ckK;
    const unsigned short* kga1 = Kh + (size_t)(w*16 + 8 + srow) * HD + (ckK ^ 32);

    // Vt read slots (old pattern)
    const int c0 = ((quad)     ^ (lq & 7)) * 8;
    const int c1 = ((4 + quad) ^ (lq & 7)) * 8;
    // K fragment read: permuted rows rho = krA + {0,4,32,36}; slots via fK
    const int fk  = (lq & 3) | (((lq >> 2) & 1) << 2);
    const int kc0 = (quad ^ fk) * 8;
    const int kc1 = kc0 ^ 32;
    const int krA = (lq >> 2) * 8 + (lq & 3);

    f32x4 zero = {0.f, 0.f, 0.f, 0.f};
    f32x4 o[4], lsum = zero;
#pragma unroll
    for (int ng = 0; ng < 4; ng++) o[ng] = zero;

    auto stage = [&](int buf, int kt) {
        GLL16(kga0 + (size_t)kt*64*HD, &Ks[buf][w*16][0]);
        GLL16(kga1 + (size_t)kt*64*HD, &Ks[buf][w*16 + 8][0]);
        GLL16(vga + kt*64,                   &Vt[buf][w*16][0]);
        GLL16(vga + kt*64 + (size_t)8*S_LEN, &Vt[buf][w*16 + 8][0]);
    };

    // per-lane mask (QK^T C-init): k = quad*8 + {0..3, 4..7, 32..35, 36..39}
    auto ldm = [&](f32x4* dst, int kt) {
        const float* mb = wsmb + kt*64 + quad*8;
        dst[0] = *(const f32x4*)(mb);
        dst[1] = *(const f32x4*)(mb + 4);
        dst[2] = *(const f32x4*)(mb + 32);
        dst[3] = *(const f32x4*)(mb + 36);
    };

    auto compute = [&](int buf, const f32x4* mk) {
        // ---- swapped QK^T with permuted K rows; mask as C-init ----
        // call c: rows rho = krA + roff[c]; st[c][r] = S^T[k=quad*8+off][q=lq]
        f32x4 st[4];
#pragma unroll
        for (int c = 0; c < 4; c++) {
            const int roff = (c & 1) * 4 + (c >> 1) * 32;
            bf16x8 b0 = *(const bf16x8*)&Ks[buf][krA + roff][kc0];
            bf16x8 b1 = *(const bf16x8*)&Ks[buf][krA + roff][kc1];
            f32x4 z = __builtin_amdgcn_mfma_f32_16x16x32_bf16(b0, a0, mk[c], 0, 0, 0);
            st[c]   = __builtin_amdgcn_mfma_f32_16x16x32_bf16(b1, a1, z,     0, 0, 0);
        }

        // ---- softmax numerator fully in-register: exp2 + cvt_pk ----
        union PU { unsigned int d[4]; bf16x8 v; } p0u, p1u;
#pragma unroll
        for (int c = 0; c < 2; c++) {
            float e0 = EXP2(st[c][0]), e1 = EXP2(st[c][1]);
            float e2 = EXP2(st[c][2]), e3 = EXP2(st[c][3]);
            p0u.d[c*2]   = cvtpk(e0, e1);
            p0u.d[c*2+1] = cvtpk(e2, e3);
        }
#pragma unroll
        for (int c = 0; c < 2; c++) {
            float e0 = EXP2(st[2+c][0]), e1 = EXP2(st[2+c][1]);
            float e2 = EXP2(st[2+c][2]), e3 = EXP2(st[2+c][3]);
            p1u.d[c*2]   = cvtpk(e0, e1);
            p1u.d[c*2+1] = cvtpk(e2, e3);
        }
        bf16x8 pa0 = p0u.v, pa1 = p1u.v;

        lsum = __builtin_amdgcn_mfma_f32_16x16x32_bf16(pa0, ones, lsum, 0, 0, 0);
        lsum = __builtin_amdgcn_mfma_f32_16x16x32_bf16(pa1, ones, lsum, 0, 0, 0);

        // ---- PV ----
#pragma unroll
        for (int ng = 0; ng < 4; ng++) {
            bf16x8 v0 = *(const bf16x8*)&Vt[buf][ng*16 + lq][c0];
            bf16x8 v1 = *(const bf16x8*)&Vt[buf][ng*16 + lq][c1];
            f32x4 t = __builtin_amdgcn_mfma_f32_16x16x32_bf16(pa0, v0, o[ng], 0, 0, 0);
            o[ng]   = __builtin_amdgcn_mfma_f32_16x16x32_bf16(pa1, v1, t,     0, 0, 0);
        }
    };

    f32x4 mkA[4], mkB[4];
    ldm(mkA, 0);
    stage(0, 0);
    __syncthreads();   // drains vmcnt (tile 0)

    for (int kt = 0; kt < S_LEN / 64; kt += 2) {
        stage(1, kt + 1); ldm(mkB, kt + 1);
        compute(0, mkA);
        __syncthreads();
        if (kt + 2 < S_LEN / 64) { stage(0, kt + 2); ldm(mkA, kt + 2); }
        compute(1, mkB);
        __syncthreads();
    }

    // epilogue: out[bi, q, hi*64 + d] fp32
#pragma unroll
    for (int r = 0; r < 4; r++) {
        const float inv = 1.0f / lsum[r];
        const int row = q0 + w*16 + quad*4 + r;
#pragma unroll
        for (int ng = 0; ng < 4; ng++)
            out[((size_t)(bi * S_LEN + row)) * HID + hi*HD + ng*16 + lq] = o[ng][r] * inv;
    }
}

extern "C" void kernel_launch(void* const* d_in, const int* in_sizes, int n_in,
                              void* d_out, int out_size, void* d_ws, size_t ws_size,
                              hipStream_t stream) {
    const float* X    = (const float*)d_in[0];
    const float* mask = (const float*)d_in[1];
    const float* Wq   = (const float*)d_in[2];
    const float* bq   = (const float*)d_in[3];
    const float* Wk   = (const float*)d_in[4];
    const float* bk   = (const float*)d_in[5];
    const float* Wv   = (const float*)d_in[6];
    const float* bv   = (const float*)d_in[7];
    float* out = (float*)d_out;

    const size_t per = (size_t)BATCH * NH * S_LEN * HD;  // 3,145,728
    unsigned short* qb = (unsigned short*)d_ws;           // Q^T [B,H,64,S]
    unsigned short* kb = qb + per;                        // K   [B,H,S,64]
    unsigned short* vb = kb + per;                        // V^T [B,H,64,S]
    unsigned short* xb = vb + per;                        // 4096*768
    unsigned short* wt = xb + (size_t)4096 * GK;          // 2304*768
    float* wsm = (float*)(wt + (size_t)2304 * GK);        // 2*2048 f32 (mask*log2e)

    prep_kernel<<<4804, 256, 0, stream>>>(X, Wq, Wk, Wv, mask, xb, wt, wsm);

    dim3 ggrid(36, 32);                   // 1152 blocks, 128x64 tiles
    gemm_qkv<<<ggrid, 256, 0, stream>>>(xb, wt, bq, bk, bv, qb, kb, vb);

    dim3 agrid(S_LEN / 64, BATCH * NH);   // (32, 24) = 768 blocks = 3/CU
    attn_kernel<<<agrid, 256, 0, stream>>>(qb, kb, vb, wsm, out);
}